// Round 1
// baseline (77.080 us; speedup 1.0000x reference)
//
#include <hip/hip_runtime.h>
#include <hip/hip_bf16.h>

#define NC 4096
#define NK 1024

static constexpr float MARGIN = 0.0001f;

typedef __attribute__((ext_vector_type(4))) float f32x4;
typedef __attribute__((ext_vector_type(8))) short bf16x8;

__device__ inline ushort f2bf_raw(float f) {
    __hip_bfloat16 h = __float2bfloat16(f);
    return *reinterpret_cast<const ushort*>(&h);
}

// One block per row: cast f32 row -> bf16, compute sum of squares (f32).
__global__ __launch_bounds__(256) void cast_sq_kernel(const float* __restrict__ x,
                                                      ushort* __restrict__ xb,
                                                      float* __restrict__ sq) {
    const int row = blockIdx.x;
    const int t = threadIdx.x;
    const float4 v = reinterpret_cast<const float4*>(x + (size_t)row * NK)[t];
    float s = v.x * v.x + v.y * v.y + v.z * v.z + v.w * v.w;
    ushort4 o;
    o.x = f2bf_raw(v.x);
    o.y = f2bf_raw(v.y);
    o.z = f2bf_raw(v.z);
    o.w = f2bf_raw(v.w);
    reinterpret_cast<ushort4*>(xb + (size_t)row * NK)[t] = o;

    #pragma unroll
    for (int off = 32; off > 0; off >>= 1) s += __shfl_down(s, off);
    __shared__ float red[4];
    const int lane = t & 63, wid = t >> 6;
    if (lane == 0) red[wid] = s;
    __syncthreads();
    if (t == 0) sq[row] = red[0] + red[1] + red[2] + red[3];
}

__global__ void zero_kernel(float* out) { out[0] = 0.f; }

#define BM 128
#define BK 64
#define LDK 72  // padded LDS row stride in bf16 elems (144 B: 16B-aligned, breaks bank conflicts)

// Upper-triangular tiled syrk with fused hinge reduction.
// 256 threads = 4 waves in 2x2; each wave owns a 64x64 output sub-tile (4x4 frags of 16x16).
__global__ __launch_bounds__(256) void gram_hinge_kernel(const ushort* __restrict__ xb,
                                                         const float* __restrict__ sq,
                                                         float* __restrict__ out) {
    const int bi = blockIdx.y, bj = blockIdx.x;
    if (bj < bi) return;  // upper triangle only (uniform across block)

    __shared__ ushort As[BM * LDK];
    __shared__ ushort Bs[BM * LDK];
    __shared__ float red[4];

    const int tid = threadIdx.x;
    const int lane = tid & 63, wid = tid >> 6;
    const int wr = wid >> 1, wc = wid & 1;

    f32x4 acc[4][4];
    #pragma unroll
    for (int m = 0; m < 4; ++m)
        #pragma unroll
        for (int n = 0; n < 4; ++n)
            acc[m][n] = f32x4{0.f, 0.f, 0.f, 0.f};

    const int rowA0 = bi * BM;
    const int rowB0 = bj * BM;

    for (int kt = 0; kt < NK / BK; ++kt) {
        const int k0 = kt * BK;
        __syncthreads();  // previous iter's reads done before overwrite
        // Stage A (128x64 bf16) and B (128x64 bf16): 4 x 16B loads each per thread.
        #pragma unroll
        for (int u = 0; u < 4; ++u) {
            const int idx = u * 256 + tid;
            const int r = idx >> 3;          // 8 chunks of 16B per 64-elem row
            const int co = (idx & 7) * 8;    // bf16 element offset in row
            *reinterpret_cast<ulonglong2*>(&As[r * LDK + co]) =
                *reinterpret_cast<const ulonglong2*>(&xb[(size_t)(rowA0 + r) * NK + k0 + co]);
            *reinterpret_cast<ulonglong2*>(&Bs[r * LDK + co]) =
                *reinterpret_cast<const ulonglong2*>(&xb[(size_t)(rowB0 + r) * NK + k0 + co]);
        }
        __syncthreads();

        #pragma unroll
        for (int kk = 0; kk < 2; ++kk) {
            const int kc = kk * 32 + (lane >> 4) * 8;
            bf16x8 a[4], b[4];
            #pragma unroll
            for (int m = 0; m < 4; ++m)
                a[m] = *reinterpret_cast<const bf16x8*>(&As[(wr * 64 + m * 16 + (lane & 15)) * LDK + kc]);
            #pragma unroll
            for (int n = 0; n < 4; ++n)
                b[n] = *reinterpret_cast<const bf16x8*>(&Bs[(wc * 64 + n * 16 + (lane & 15)) * LDK + kc]);
            #pragma unroll
            for (int m = 0; m < 4; ++m)
                #pragma unroll
                for (int n = 0; n < 4; ++n)
                    acc[m][n] = __builtin_amdgcn_mfma_f32_16x16x32_bf16(a[m], b[n], acc[m][n], 0, 0, 0);
        }
    }

    // Fused epilogue: d2 = sq[i] + sq[j] - 2*g ; hinge; mask i<j ; reduce.
    // C/D layout (16x16x32 bf16): col = lane&15, row = (lane>>4)*4 + j   [m89]
    float local = 0.f;
    const int r0 = rowA0 + wr * 64 + (lane >> 4) * 4;
    const int c0 = rowB0 + wc * 64 + (lane & 15);
    #pragma unroll
    for (int n = 0; n < 4; ++n) {
        const int c = c0 + n * 16;
        const float sqc = sq[c];
        #pragma unroll
        for (int m = 0; m < 4; ++m) {
            const int rbase = r0 + m * 16;
            #pragma unroll
            for (int j = 0; j < 4; ++j) {
                const int i = rbase + j;
                if (i < c) {
                    const float d2 = sq[i] + sqc - 2.f * acc[m][n][j];
                    const float d = sqrtf(fmaxf(d2, 0.f));
                    local += fmaxf(MARGIN - d, 0.f);
                }
            }
        }
    }
    #pragma unroll
    for (int off = 32; off > 0; off >>= 1) local += __shfl_down(local, off);
    if (lane == 0) red[wid] = local;
    __syncthreads();
    if (tid == 0) atomicAdd(out, red[0] + red[1] + red[2] + red[3]);
}

extern "C" void kernel_launch(void* const* d_in, const int* in_sizes, int n_in,
                              void* d_out, int out_size, void* d_ws, size_t ws_size,
                              hipStream_t stream) {
    const float* x = (const float*)d_in[0];
    float* out = (float*)d_out;
    ushort* xb = (ushort*)d_ws;                                           // 8 MB bf16 matrix
    float* sq = (float*)((char*)d_ws + (size_t)NC * NK * sizeof(ushort)); // 16 KB row norms

    cast_sq_kernel<<<NC, 256, 0, stream>>>(x, xb, sq);
    zero_kernel<<<1, 1, 0, stream>>>(out);
    dim3 grid(NC / BM, NC / BM);
    gram_hinge_kernel<<<grid, 256, 0, stream>>>(xb, sq, out);
}

// Round 2
// 71.852 us; speedup vs baseline: 1.0728x; 1.0728x over previous
//
#include <hip/hip_runtime.h>
#include <hip/hip_bf16.h>

#define NC 4096
#define NK 1024
#define NT (NC / 128)              // 32 row/col tiles
#define NBLK (NT * (NT + 1) / 2)   // 528 upper-triangular blocks

static constexpr float MARGIN = 0.0001f;

typedef __attribute__((ext_vector_type(4))) float f32x4;
typedef __attribute__((ext_vector_type(8))) short bf16x8;

__device__ inline ushort f2bf_raw(float f) {
    __hip_bfloat16 h = __float2bfloat16(f);
    return *reinterpret_cast<const ushort*>(&h);
}

// Async 16B global -> LDS. LDS dest must be wave-uniform; HW writes dst + lane*16.
__device__ inline void gload16(const ushort* g, ushort* l) {
    __builtin_amdgcn_global_load_lds(
        (const __attribute__((address_space(1))) void*)g,
        (__attribute__((address_space(3))) void*)l,
        16, 0, 0);
}

// One block per row: cast f32 row -> bf16, compute sum of squares (f32).
__global__ __launch_bounds__(256) void cast_sq_kernel(const float* __restrict__ x,
                                                      ushort* __restrict__ xb,
                                                      float* __restrict__ sq) {
    const int row = blockIdx.x;
    const int t = threadIdx.x;
    const float4 v = reinterpret_cast<const float4*>(x + (size_t)row * NK)[t];
    float s = v.x * v.x + v.y * v.y + v.z * v.z + v.w * v.w;
    ushort4 o;
    o.x = f2bf_raw(v.x);
    o.y = f2bf_raw(v.y);
    o.z = f2bf_raw(v.z);
    o.w = f2bf_raw(v.w);
    reinterpret_cast<ushort4*>(xb + (size_t)row * NK)[t] = o;

    #pragma unroll
    for (int off = 32; off > 0; off >>= 1) s += __shfl_down(s, off);
    __shared__ float red[4];
    const int lane = t & 63, wid = t >> 6;
    if (lane == 0) red[wid] = s;
    __syncthreads();
    if (t == 0) sq[row] = red[0] + red[1] + red[2] + red[3];
}

__global__ void zero_kernel(float* out) { out[0] = 0.f; }

// Upper-triangular tiled syrk (128x128 tile, BK=64) with fused hinge reduction.
// Staging: global_load_lds width-16 into LINEAR LDS; source pre-swizzled with
// granule ^= (row&7) so the swizzled ds_read_b128 is bank-conflict-reasonable
// (rule #21: swizzle both sides or neither).
__global__ __launch_bounds__(256) void gram_hinge_kernel(const ushort* __restrict__ xb,
                                                         const float* __restrict__ sq,
                                                         float* __restrict__ out) {
    // Triangular decode: block t -> (bi, bj) with bi <= bj.
    int rem = blockIdx.x;
    int bi = 0;
    while (rem >= NT - bi) { rem -= NT - bi; ++bi; }
    const int bj = bi + rem;

    __shared__ ushort As[128 * 64];  // 16 KB, linear [row][col], 16B granules swizzled
    __shared__ ushort Bs[128 * 64];
    __shared__ float red[4];

    const int tid = threadIdx.x;
    const int lane = tid & 63, wid = tid >> 6;
    const int wr = wid >> 1, wc = wid & 1;

    f32x4 acc[4][4];
    #pragma unroll
    for (int m = 0; m < 4; ++m)
        #pragma unroll
        for (int n = 0; n < 4; ++n)
            acc[m][n] = f32x4{0.f, 0.f, 0.f, 0.f};

    const int rowA0 = bi * 128;
    const int rowB0 = bj * 128;

    for (int kt = 0; kt < NK / 64; ++kt) {
        const int k0 = kt * 64;
        __syncthreads();  // previous iter's ds_reads done before overwrite
        // Stage A and B (each 128 rows x 64 cols bf16 = 1024 granules of 16B).
        // Wave w, call u covers granules [w*256 + u*64 + lane]; granule G sits at
        // LDS (row=G>>3, cl=G&7) and must hold global granule cg = cl ^ (row&7).
        #pragma unroll
        for (int u = 0; u < 4; ++u) {
            const int row = wid * 32 + u * 8 + (lane >> 3);
            const int cg = (lane & 7) ^ (row & 7);
            const size_t goff = (size_t)row * NK + k0 + cg * 8;
            gload16(xb + (size_t)rowA0 * NK + goff, &As[(wid * 256 + u * 64) * 8]);
            gload16(xb + (size_t)rowB0 * NK + goff, &Bs[(wid * 256 + u * 64) * 8]);
        }
        __syncthreads();  // drains vmcnt (compiler-inserted) — data ready

        #pragma unroll
        for (int kk = 0; kk < 2; ++kk) {
            bf16x8 a[4], b[4];
            #pragma unroll
            for (int m = 0; m < 4; ++m) {
                const int row = wr * 64 + m * 16 + (lane & 15);
                const int sc = ((kk * 4 + (lane >> 4)) ^ (row & 7)) * 8;
                a[m] = *reinterpret_cast<const bf16x8*>(&As[row * 64 + sc]);
            }
            #pragma unroll
            for (int n = 0; n < 4; ++n) {
                const int row = wc * 64 + n * 16 + (lane & 15);
                const int sc = ((kk * 4 + (lane >> 4)) ^ (row & 7)) * 8;
                b[n] = *reinterpret_cast<const bf16x8*>(&Bs[row * 64 + sc]);
            }
            #pragma unroll
            for (int m = 0; m < 4; ++m)
                #pragma unroll
                for (int n = 0; n < 4; ++n)
                    acc[m][n] = __builtin_amdgcn_mfma_f32_16x16x32_bf16(a[m], b[n], acc[m][n], 0, 0, 0);
        }
    }

    // Fused epilogue: d2 = sq[i] + sq[j] - 2*g ; hinge; mask i<j ; reduce.
    // C/D layout (16x16x32 bf16): col = lane&15, row = (lane>>4)*4 + j   [m89]
    float local = 0.f;
    const int r0 = rowA0 + wr * 64 + (lane >> 4) * 4;
    const int c0 = rowB0 + wc * 64 + (lane & 15);
    #pragma unroll
    for (int n = 0; n < 4; ++n) {
        const int c = c0 + n * 16;
        const float sqc = sq[c];
        #pragma unroll
        for (int m = 0; m < 4; ++m) {
            const int rbase = r0 + m * 16;
            #pragma unroll
            for (int j = 0; j < 4; ++j) {
                const int i = rbase + j;
                if (i < c) {
                    const float d2 = sq[i] + sqc - 2.f * acc[m][n][j];
                    const float d = sqrtf(fmaxf(d2, 0.f));
                    local += fmaxf(MARGIN - d, 0.f);
                }
            }
        }
    }
    #pragma unroll
    for (int off = 32; off > 0; off >>= 1) local += __shfl_down(local, off);
    if (lane == 0) red[wid] = local;
    __syncthreads();
    if (tid == 0) atomicAdd(out, red[0] + red[1] + red[2] + red[3]);
}

extern "C" void kernel_launch(void* const* d_in, const int* in_sizes, int n_in,
                              void* d_out, int out_size, void* d_ws, size_t ws_size,
                              hipStream_t stream) {
    const float* x = (const float*)d_in[0];
    float* out = (float*)d_out;
    ushort* xb = (ushort*)d_ws;                                           // 8 MB bf16 matrix
    float* sq = (float*)((char*)d_ws + (size_t)NC * NK * sizeof(ushort)); // 16 KB row norms

    cast_sq_kernel<<<NC, 256, 0, stream>>>(x, xb, sq);
    zero_kernel<<<1, 1, 0, stream>>>(out);
    gram_hinge_kernel<<<NBLK, 256, 0, stream>>>(xb, sq, out);
}

// Round 3
// 61.749 us; speedup vs baseline: 1.2483x; 1.1636x over previous
//
#include <hip/hip_runtime.h>
#include <hip/hip_bf16.h>

#define NC 4096
#define NK 1024
#define NT (NC / 128)              // 32 row/col tiles
#define NBLK (NT * (NT + 1) / 2)   // 528 upper-triangular blocks (= 8 XCDs * 66)

static constexpr float MARGIN = 0.0001f;

typedef __attribute__((ext_vector_type(4))) float f32x4;
typedef __attribute__((ext_vector_type(8))) short bf16x8;

__device__ inline ushort f2bf_raw(float f) {
    __hip_bfloat16 h = __float2bfloat16(f);
    return *reinterpret_cast<const ushort*>(&h);
}

// Async 16B global -> LDS. LDS dest is wave-uniform; HW writes dst + lane*16.
__device__ inline void gload16(const ushort* g, ushort* l) {
    __builtin_amdgcn_global_load_lds(
        (const __attribute__((address_space(1))) void*)g,
        (__attribute__((address_space(3))) void*)l,
        16, 0, 0);
}

// One block per row: cast f32 row -> bf16, compute sum of squares (f32).
__global__ __launch_bounds__(256) void cast_sq_kernel(const float* __restrict__ x,
                                                      ushort* __restrict__ xb,
                                                      float* __restrict__ sq) {
    const int row = blockIdx.x;
    const int t = threadIdx.x;
    const float4 v = reinterpret_cast<const float4*>(x + (size_t)row * NK)[t];
    float s = v.x * v.x + v.y * v.y + v.z * v.z + v.w * v.w;
    ushort4 o;
    o.x = f2bf_raw(v.x);
    o.y = f2bf_raw(v.y);
    o.z = f2bf_raw(v.z);
    o.w = f2bf_raw(v.w);
    reinterpret_cast<ushort4*>(xb + (size_t)row * NK)[t] = o;

    #pragma unroll
    for (int off = 32; off > 0; off >>= 1) s += __shfl_down(s, off);
    __shared__ float red[4];
    const int lane = t & 63, wid = t >> 6;
    if (lane == 0) red[wid] = s;
    __syncthreads();
    if (t == 0) sq[row] = red[0] + red[1] + red[2] + red[3];
}

__global__ void zero_kernel(float* out) { out[0] = 0.f; }

// Upper-triangular tiled syrk (128x128 tile, BK=64) with fused hinge reduction.
// 2-phase double-buffered pipeline: STAGE(next) issued before COMPUTE(cur);
// raw s_barrier + counted vmcnt(8) keep next tile's loads in flight across
// the compute phase (T3/T4 minimum recipe). LDS linear, 16B-granule XOR
// swizzle on both the global source and the ds_read side (rule #21).
__global__ __launch_bounds__(256) void gram_hinge_kernel(const ushort* __restrict__ xb,
                                                         const float* __restrict__ sq,
                                                         float* __restrict__ out) {
    // XCD-aware chunking: 528 = 8 * 66 exactly -> bijective.
    const int wgid = (blockIdx.x & 7) * (NBLK / 8) + (blockIdx.x >> 3);
    // Triangular decode: wgid -> (bi, bj), bi <= bj, bj fastest within a bi-run.
    int rem = wgid;
    int bi = 0;
    while (rem >= NT - bi) { rem -= NT - bi; ++bi; }
    const int bj = bi + rem;

    __shared__ ushort As[2][128 * 64];  // 2 x 16 KB per matrix
    __shared__ ushort Bs[2][128 * 64];
    __shared__ float red[4];

    const int tid = threadIdx.x;
    const int lane = tid & 63, wid = tid >> 6;
    const int wr = wid >> 1, wc = wid & 1;

    const int rowA0 = bi * 128;
    const int rowB0 = bj * 128;

    // Pre-load epilogue row/col norms into registers BEFORE any staging so the
    // vmcnt counting below only sees the 8-per-stage global_load_lds ops as
    // the newest outstanding ops (vmcnt retires in order).
    const int r0 = rowA0 + wr * 64 + (lane >> 4) * 4;
    const int c0 = rowB0 + wc * 64 + (lane & 15);
    float sqr[4][4], sqc[4];
    #pragma unroll
    for (int m = 0; m < 4; ++m)
        #pragma unroll
        for (int j = 0; j < 4; ++j) sqr[m][j] = sq[r0 + m * 16 + j];
    #pragma unroll
    for (int n = 0; n < 4; ++n) sqc[n] = sq[c0 + n * 16];

    f32x4 acc[4][4];
    #pragma unroll
    for (int m = 0; m < 4; ++m)
        #pragma unroll
        for (int n = 0; n < 4; ++n)
            acc[m][n] = f32x4{0.f, 0.f, 0.f, 0.f};

    // Stage A and B K-tiles (each 128x64 bf16 = 1024 granules of 16B) into buf.
    // Granule G=(wid*256+u*64+lane): row=G>>3, cl=G&7 holds global granule
    // cg = cl ^ (row&7)  (inverse-swizzled source, linear LDS dest).
    auto STAGE = [&](int buf, int kt) {
        const int k0 = kt * 64;
        #pragma unroll
        for (int u = 0; u < 4; ++u) {
            const int row = wid * 32 + u * 8 + (lane >> 3);
            const int cg = (lane & 7) ^ (row & 7);
            const size_t goff = (size_t)row * NK + k0 + cg * 8;
            gload16(xb + (size_t)rowA0 * NK + goff, &As[buf][(wid * 256 + u * 64) * 8]);
            gload16(xb + (size_t)rowB0 * NK + goff, &Bs[buf][(wid * 256 + u * 64) * 8]);
        }
    };

    auto COMPUTE = [&](int buf) {
        #pragma unroll
        for (int kk = 0; kk < 2; ++kk) {
            const int kgrp = kk * 4 + (lane >> 4);
            bf16x8 a[4], b[4];
            #pragma unroll
            for (int m = 0; m < 4; ++m) {
                const int row = wr * 64 + m * 16 + (lane & 15);
                const int sc = (kgrp ^ (row & 7)) * 8;
                a[m] = *reinterpret_cast<const bf16x8*>(&As[buf][row * 64 + sc]);
            }
            #pragma unroll
            for (int n = 0; n < 4; ++n) {
                const int row = wc * 64 + n * 16 + (lane & 15);
                const int sc = (kgrp ^ (row & 7)) * 8;
                b[n] = *reinterpret_cast<const bf16x8*>(&Bs[buf][row * 64 + sc]);
            }
            #pragma unroll
            for (int m = 0; m < 4; ++m)
                #pragma unroll
                for (int n = 0; n < 4; ++n)
                    acc[m][n] = __builtin_amdgcn_mfma_f32_16x16x32_bf16(a[m], b[n], acc[m][n], 0, 0, 0);
        }
    };

    STAGE(0, 0);
    int cur = 0;
    for (int kt = 0; kt < NK / 64 - 1; ++kt) {
        STAGE(cur ^ 1, kt + 1);                       // 8 new vmem ops in flight
        asm volatile("s_waitcnt vmcnt(8)" ::: "memory");  // oldest 8 (cur tile) done
        __builtin_amdgcn_s_barrier();                 // all waves' cur-tile data ready
        __builtin_amdgcn_sched_barrier(0);
        COMPUTE(cur);
        __builtin_amdgcn_sched_barrier(0);
        __builtin_amdgcn_s_barrier();                 // all reads of cur done -> safe to overwrite next iter
        cur ^= 1;
    }
    asm volatile("s_waitcnt vmcnt(0)" ::: "memory");
    __builtin_amdgcn_s_barrier();
    __builtin_amdgcn_sched_barrier(0);
    COMPUTE(cur);

    // Fused epilogue: d2 = sq[i] + sq[j] - 2*g ; hinge; mask i<j ; reduce.
    // C/D layout (16x16x32 bf16): col = lane&15, row = (lane>>4)*4 + j   [m89]
    float local = 0.f;
    #pragma unroll
    for (int n = 0; n < 4; ++n) {
        const int c = c0 + n * 16;
        #pragma unroll
        for (int m = 0; m < 4; ++m) {
            #pragma unroll
            for (int j = 0; j < 4; ++j) {
                const int i = r0 + m * 16 + j;
                if (i < c) {
                    const float d2 = sqr[m][j] + sqc[n] - 2.f * acc[m][n][j];
                    const float d = sqrtf(fmaxf(d2, 0.f));
                    local += fmaxf(MARGIN - d, 0.f);
                }
            }
        }
    }
    #pragma unroll
    for (int off = 32; off > 0; off >>= 1) local += __shfl_down(local, off);
    if (lane == 0) red[wid] = local;
    __syncthreads();
    if (tid == 0) atomicAdd(out, red[0] + red[1] + red[2] + red[3]);
}

extern "C" void kernel_launch(void* const* d_in, const int* in_sizes, int n_in,
                              void* d_out, int out_size, void* d_ws, size_t ws_size,
                              hipStream_t stream) {
    const float* x = (const float*)d_in[0];
    float* out = (float*)d_out;
    ushort* xb = (ushort*)d_ws;                                           // 8 MB bf16 matrix
    float* sq = (float*)((char*)d_ws + (size_t)NC * NK * sizeof(ushort)); // 16 KB row norms

    cast_sq_kernel<<<NC, 256, 0, stream>>>(x, xb, sq);
    zero_kernel<<<1, 1, 0, stream>>>(out);
    gram_hinge_kernel<<<NBLK, 256, 0, stream>>>(xb, sq, out);
}

// Round 4
// 53.446 us; speedup vs baseline: 1.4422x; 1.1553x over previous
//
#include <hip/hip_runtime.h>
#include <hip/hip_bf16.h>

#define NC 4096
#define NK 1024
#define NTI (NC / 64)    // 64 row tiles (i, 64 rows each)
#define NTJ (NC / 128)   // 32 col tiles (j, 128 cols each)
// live blocks: bi <= 2*bj+1  ->  sum_{bj=0}^{31} (2*bj+2) = 1056 = 8 * 132
#define NBLK 1056

static constexpr float MARGIN = 0.0001f;

typedef __attribute__((ext_vector_type(4))) float f32x4;
typedef __attribute__((ext_vector_type(8))) short bf16x8;

__device__ inline ushort f2bf_raw(float f) {
    __hip_bfloat16 h = __float2bfloat16(f);
    return *reinterpret_cast<const ushort*>(&h);
}

// Async 16B global -> LDS. LDS dest is wave-uniform; HW writes dst + lane*16.
__device__ inline void gload16(const ushort* g, ushort* l) {
    __builtin_amdgcn_global_load_lds(
        (const __attribute__((address_space(1))) void*)g,
        (__attribute__((address_space(3))) void*)l,
        16, 0, 0);
}

// One block per row: cast f32 row -> bf16, compute sum of squares (f32).
__global__ __launch_bounds__(256) void cast_sq_kernel(const float* __restrict__ x,
                                                      ushort* __restrict__ xb,
                                                      float* __restrict__ sq) {
    const int row = blockIdx.x;
    const int t = threadIdx.x;
    const float4 v = reinterpret_cast<const float4*>(x + (size_t)row * NK)[t];
    float s = v.x * v.x + v.y * v.y + v.z * v.z + v.w * v.w;
    ushort4 o;
    o.x = f2bf_raw(v.x);
    o.y = f2bf_raw(v.y);
    o.z = f2bf_raw(v.z);
    o.w = f2bf_raw(v.w);
    reinterpret_cast<ushort4*>(xb + (size_t)row * NK)[t] = o;

    #pragma unroll
    for (int off = 32; off > 0; off >>= 1) s += __shfl_down(s, off);
    __shared__ float red[4];
    const int lane = t & 63, wid = t >> 6;
    if (lane == 0) red[wid] = s;
    __syncthreads();
    if (t == 0) sq[row] = red[0] + red[1] + red[2] + red[3];
}

__global__ void zero_kernel(float* out) { out[0] = 0.f; }

// Upper-triangular tiled syrk with fused hinge reduction.
// 64x128 rectangular tiles (1056 live blocks -> ~4 blocks/CU grid, 48 KB LDS
// -> 3 resident blocks/CU = 3 waves/SIMD: TLP fix for the round-3 latency
// stall). 4 waves of 32x64 (2x4 frags). 2-phase double-buffered pipeline with
// counted vmcnt(6); 16B-granule XOR swizzle on both sides (rule #21).
__global__ __launch_bounds__(256) void gram_hinge_kernel(const ushort* __restrict__ xb,
                                                         const float* __restrict__ sq,
                                                         float* __restrict__ out) {
    // XCD-aware chunking: 1056 = 8 * 132 exactly -> bijective. Consecutive
    // wgid share a B-panel (same bj run) -> per-XCD L2 locality.
    const int wgid = (blockIdx.x & 7) * (NBLK / 8) + (blockIdx.x >> 3);
    // Decode: runs of bi for each bj; run length = 2*bj+2 (bi in [0, 2*bj+1]).
    int rem = wgid;
    int bj = 0;
    while (rem >= 2 * bj + 2) { rem -= 2 * bj + 2; ++bj; }
    const int bi = rem;

    __shared__ ushort As[2][64 * 64];    // 2 x 8 KB
    __shared__ ushort Bs[2][128 * 64];   // 2 x 16 KB
    __shared__ float red[4];

    const int tid = threadIdx.x;
    const int lane = tid & 63, wid = tid >> 6;
    const int wr = wid >> 1, wc = wid & 1;   // wave -> 32-row half x 64-col half

    const int rowA0 = bi * 64;
    const int rowB0 = bj * 128;

    // Epilogue norms into registers BEFORE staging (older vmem ops retire
    // first, so the counted vmcnt below stays valid regardless).
    const int r0 = rowA0 + wr * 32 + (lane >> 4) * 4;
    const int c0 = rowB0 + wc * 64 + (lane & 15);
    float sqr[2][4], sqc[4];
    #pragma unroll
    for (int m = 0; m < 2; ++m)
        #pragma unroll
        for (int j = 0; j < 4; ++j) sqr[m][j] = sq[r0 + m * 16 + j];
    #pragma unroll
    for (int n = 0; n < 4; ++n) sqc[n] = sq[c0 + n * 16];

    f32x4 acc[2][4];
    #pragma unroll
    for (int m = 0; m < 2; ++m)
        #pragma unroll
        for (int n = 0; n < 4; ++n)
            acc[m][n] = f32x4{0.f, 0.f, 0.f, 0.f};

    // Stage one K-tile: A 64x64 (512 granules of 16B), B 128x64 (1024 granules).
    // Granule G at LDS (row=G>>3, cl=G&7) holds global granule cg = cl^(row&7).
    // Per wave: 2 A-instrs + 4 B-instrs = 6 vmem ops.
    auto STAGE = [&](int buf, int kt) {
        const int k0 = kt * 64;
        #pragma unroll
        for (int u = 0; u < 2; ++u) {
            const int row = wid * 16 + u * 8 + (lane >> 3);
            const int cg = (lane & 7) ^ (row & 7);
            gload16(xb + (size_t)(rowA0 + row) * NK + k0 + cg * 8,
                    &As[buf][(wid * 128 + u * 64) * 8]);
        }
        #pragma unroll
        for (int u = 0; u < 4; ++u) {
            const int row = wid * 32 + u * 8 + (lane >> 3);
            const int cg = (lane & 7) ^ (row & 7);
            gload16(xb + (size_t)(rowB0 + row) * NK + k0 + cg * 8,
                    &Bs[buf][(wid * 256 + u * 64) * 8]);
        }
    };

    auto COMPUTE = [&](int buf) {
        #pragma unroll
        for (int kk = 0; kk < 2; ++kk) {
            const int kgrp = kk * 4 + (lane >> 4);
            bf16x8 a[2], b[4];
            #pragma unroll
            for (int m = 0; m < 2; ++m) {
                const int row = wr * 32 + m * 16 + (lane & 15);
                a[m] = *reinterpret_cast<const bf16x8*>(&As[buf][row * 64 + (kgrp ^ (row & 7)) * 8]);
            }
            #pragma unroll
            for (int n = 0; n < 4; ++n) {
                const int row = wc * 64 + n * 16 + (lane & 15);
                b[n] = *reinterpret_cast<const bf16x8*>(&Bs[buf][row * 64 + (kgrp ^ (row & 7)) * 8]);
            }
            #pragma unroll
            for (int m = 0; m < 2; ++m)
                #pragma unroll
                for (int n = 0; n < 4; ++n)
                    acc[m][n] = __builtin_amdgcn_mfma_f32_16x16x32_bf16(a[m], b[n], acc[m][n], 0, 0, 0);
        }
    };

    STAGE(0, 0);
    int cur = 0;
    for (int kt = 0; kt < NK / 64 - 1; ++kt) {
        STAGE(cur ^ 1, kt + 1);                           // 6 new vmem ops in flight
        asm volatile("s_waitcnt vmcnt(6)" ::: "memory");  // everything older (cur tile) done
        __builtin_amdgcn_s_barrier();
        __builtin_amdgcn_sched_barrier(0);
        COMPUTE(cur);
        __builtin_amdgcn_sched_barrier(0);
        __builtin_amdgcn_s_barrier();                     // reads of cur done -> overwrite ok
        cur ^= 1;
    }
    asm volatile("s_waitcnt vmcnt(0)" ::: "memory");
    __builtin_amdgcn_s_barrier();
    __builtin_amdgcn_sched_barrier(0);
    COMPUTE(cur);

    // Fused epilogue: d2 = sq[i] + sq[j] - 2*g ; hinge; mask i<j ; reduce.
    // C/D layout (16x16x32 bf16): col = lane&15, row = (lane>>4)*4 + j   [m89]
    float local = 0.f;
    #pragma unroll
    for (int n = 0; n < 4; ++n) {
        const int c = c0 + n * 16;
        #pragma unroll
        for (int m = 0; m < 2; ++m) {
            #pragma unroll
            for (int j = 0; j < 4; ++j) {
                const int i = r0 + m * 16 + j;
                if (i < c) {
                    const float d2 = sqr[m][j] + sqc[n] - 2.f * acc[m][n][j];
                    const float d = sqrtf(fmaxf(d2, 0.f));
                    local += fmaxf(MARGIN - d, 0.f);
                }
            }
        }
    }
    #pragma unroll
    for (int off = 32; off > 0; off >>= 1) local += __shfl_down(local, off);
    if (lane == 0) red[wid] = local;
    __syncthreads();
    if (tid == 0) atomicAdd(out, red[0] + red[1] + red[2] + red[3]);
}

extern "C" void kernel_launch(void* const* d_in, const int* in_sizes, int n_in,
                              void* d_out, int out_size, void* d_ws, size_t ws_size,
                              hipStream_t stream) {
    const float* x = (const float*)d_in[0];
    float* out = (float*)d_out;
    ushort* xb = (ushort*)d_ws;                                           // 8 MB bf16 matrix
    float* sq = (float*)((char*)d_ws + (size_t)NC * NK * sizeof(ushort)); // 16 KB row norms

    cast_sq_kernel<<<NC, 256, 0, stream>>>(x, xb, sq);
    zero_kernel<<<1, 1, 0, stream>>>(out);
    gram_hinge_kernel<<<NBLK, 256, 0, stream>>>(xb, sq, out);
}